// Round 11
// baseline (187.138 us; speedup 1.0000x reference)
//
#include <hip/hip_runtime.h>
#include <hip/hip_bf16.h>
#include <hip/hip_cooperative_groups.h>

namespace cg = cooperative_groups;

#define BB 16
#define FF 128
#define HH 144
#define EE 24
#define C0C 12

typedef float v4f __attribute__((ext_vector_type(4)));

// Workspace (floats): num_t/den_t: [B][F+1][H]
#define TABLE_ELEMS (BB * (FF + 1) * HH)

__device__ __forceinline__ float fastdiv(float n, float d) {
    float r = __builtin_amdgcn_rcpf(d);
    r = fmaf(fmaf(-d, r, 1.0f), r, r);   // one Newton iteration
    return n * r;
}

// Zero the e<s prefix rows of slab sp and slab 127-sp of batch b.
__device__ __forceinline__ void zero_pair(float* __restrict__ out, int pr, int tid) {
    const int x = pr & 7;
    const int t = pr >> 3;             // 0..127
    const int b = 2 * x + (t >= 64);
    const int sp = (t >= 64) ? t - 64 : t;   // 0..63
    float* out_b = out + (size_t)b * (FF * FF * HH);

    v4f* r1 = reinterpret_cast<v4f*>(out_b + (size_t)sp * FF * HH);
    const int n1 = sp * (HH / 4);
    for (int c = tid; c < n1; c += 256) r1[c] = (v4f)(0.f);

    v4f* r2 = reinterpret_cast<v4f*>(out_b + (size_t)(127 - sp) * FF * HH);
    const int n2 = (127 - sp) * (HH / 4);
    for (int c = tid; c < n2; c += 256) r2[c] = (v4f)(0.f);
}

// Full compute triangle of slab s: rows e in [s,128), r = tid/36, step 7.
__device__ __forceinline__ void comp_slab(
    const float* __restrict__ nb, const float* __restrict__ db,
    float* __restrict__ out_b, int s, int tid)
{
    float* ob = out_b + (size_t)s * (FF * HH);
    if (tid < 252) {
        const int r = tid / 36;                   // 0..6
        const int hq = tid - r * 36;              // 0..35
        const int h = hq * 4;

        const v4f n0 = *reinterpret_cast<const v4f*>(nb + (size_t)s * HH + h);
        const v4f d0 = *reinterpret_cast<const v4f*>(db + (size_t)s * HH + h);

        const float* pn = nb + (size_t)(s + r + 1) * HH + h;
        const float* pd_ = db + (size_t)(s + r + 1) * HH + h;
        float* po = ob + (size_t)(s + r) * HH + h;

        #pragma unroll 2
        for (int e = s + r; e < FF; e += 7) {
            const v4f n1 = *reinterpret_cast<const v4f*>(pn);
            const v4f d1 = *reinterpret_cast<const v4f*>(pd_);
            v4f val;
            val.x = fastdiv(n1.x - n0.x, d1.x - d0.x);
            val.y = fastdiv(n1.y - n0.y, d1.y - d0.y);
            val.z = fastdiv(n1.z - n0.z, d1.z - d0.z);
            val.w = fastdiv(n1.w - n0.w, d1.w - d0.w);
            *reinterpret_cast<v4f*>(po) = val;
            pn += 7 * HH;
            pd_ += 7 * HH;
            po += 7 * HH;
        }
    }
}

// Cooperative single kernel, grid 1024 x 256 (4 blocks/CU).
// Phase 1: blocks 0..143 build prefix tables (b,16-h tile); blocks 144..1023
//          zero-fill the e<s triangle (144 of them take a double share).
// grid.sync()
// Phase 2: all blocks write the compute triangle, pair (sp, 127-sp).
__global__ __launch_bounds__(256, 4) void seg_coop(
    const float* __restrict__ note,   // [B][F][E]
    const float* __restrict__ hv,     // [B][H][E]
    const float* __restrict__ W0,
    const float* __restrict__ b0,
    const float* __restrict__ W1,
    const float* __restrict__ b1,
    const float* __restrict__ Wc,
    const float* __restrict__ bc,
    float* __restrict__ num_t,
    float* __restrict__ den_t,
    float* __restrict__ out)          // [B][F(s)][F(e)][H]
{
    const int blk = blockIdx.x;
    const int tid = threadIdx.x;

    __shared__ float s_note[FF * EE];  // 12 KB
    __shared__ float s_hcat[16][EE];
    __shared__ float s_q[16][EE];
    __shared__ float s_p[FF][16];      // 8 KB
    __shared__ float s_pd[FF][16];     // 8 KB
    __shared__ float s_pm[16][16];
    __shared__ float s_m[16];

    if (blk < 144) {
        // ---- table block: one per (b, 16-h tile) ----
        const int x = blk & 7;
        const int t = blk >> 3;            // 0..17
        const int b = 2 * x + (t >= 9);
        const int tile = (t >= 9) ? t - 9 : t;   // 0..8
        const int h0 = tile * 16;

        const float* nb_ = note + (size_t)b * FF * EE;
        for (int k = tid; k < FF * EE / 4; k += 256)
            reinterpret_cast<v4f*>(s_note)[k] = reinterpret_cast<const v4f*>(nb_)[k];

        for (int idx = tid; idx < 16 * EE; idx += 256) {
            const int hl = idx / EE, e = idx - hl * EE;
            const float* hvb = hv + ((size_t)b * HH + h0 + hl) * EE;
            float acc;
            if (e < C0C) {
                acc = b0[e];
                #pragma unroll
                for (int j = 0; j < C0C; ++j) acc += W0[e * C0C + j] * hvb[j];
            } else {
                const int e1 = e - C0C;
                acc = b1[e1];
                #pragma unroll
                for (int j = 0; j < C0C; ++j) acc += W1[e1 * C0C + j] * hvb[C0C + j];
            }
            s_hcat[hl][e] = acc;
        }
        __syncthreads();
        for (int idx = tid; idx < 16 * EE; idx += 256) {
            const int hl = idx / EE, e = idx - hl * EE;
            float acc = bc[e];
            #pragma unroll
            for (int j = 0; j < EE; ++j) acc += Wc[e * EE + j] * s_hcat[hl][j];
            s_q[hl][e] = acc;
        }
        __syncthreads();

        const int hl = tid & 15;
        const int f0 = tid >> 4;
        const float scale = 0.20412414523193150818f;  // 1/sqrt(24)

        float dv[8];
        float pmax = -3.4e38f;
        #pragma unroll
        for (int k = 0; k < 8; ++k) {
            const int f = f0 + (k << 4);
            float acc = 0.f;
            #pragma unroll
            for (int e = 0; e < EE; ++e) acc += s_q[hl][e] * s_note[f * EE + e];
            dv[k] = acc;
            pmax = fmaxf(pmax, acc);
        }
        s_pm[f0][hl] = pmax * scale;
        __syncthreads();
        if (tid < 16) {
            float m = s_pm[0][tid];
            #pragma unroll
            for (int r = 1; r < 16; ++r) m = fmaxf(m, s_pm[r][tid]);
            s_m[tid] = m;
        }
        __syncthreads();
        const float m = s_m[hl];

        #pragma unroll
        for (int k = 0; k < 8; ++k) {
            const int f = f0 + (k << 4);
            const float p = __expf(dv[k] * scale - m);
            s_p[f][hl] = p;
            s_pd[f][hl] = p * dv[k];
        }
        __syncthreads();

        for (int off = 1; off < FF; off <<= 1) {
            float tp[8], tpd[8];
            #pragma unroll
            for (int k = 0; k < 8; ++k) {
                const int f = f0 + (k << 4);
                tp[k] = (f >= off) ? s_p[f - off][hl] : 0.f;
                tpd[k] = (f >= off) ? s_pd[f - off][hl] : 0.f;
            }
            __syncthreads();
            #pragma unroll
            for (int k = 0; k < 8; ++k) {
                const int f = f0 + (k << 4);
                if (f >= off) { s_p[f][hl] += tp[k]; s_pd[f][hl] += tpd[k]; }
            }
            __syncthreads();
        }

        const size_t base = (size_t)b * (FF + 1) * HH + h0;
        for (int idx4 = tid; idx4 < 512; idx4 += 256) {
            const int f = idx4 >> 2;           // 0..127
            const int hh = (idx4 & 3) * 4;     // 0,4,8,12
            *reinterpret_cast<v4f*>(num_t + base + (size_t)(f + 1) * HH + hh) =
                *reinterpret_cast<const v4f*>(&s_pd[f][hh]);
            *reinterpret_cast<v4f*>(den_t + base + (size_t)(f + 1) * HH + hh) =
                *reinterpret_cast<const v4f*>(&s_p[f][hh]);
        }
        if (tid < 16) {
            num_t[base + tid] = 0.f;
            den_t[base + tid] = 0.f;
        }
    } else {
        // ---- zero-fill blocks: pair (blk-144); 144 blocks take a 2nd pair ----
        const int zp = blk - 144;          // 0..879
        zero_pair(out, zp, tid);
        if (zp < 144) zero_pair(out, 880 + zp, tid);
    }

    cg::this_grid().sync();

    // ---- Phase 2: compute triangle, pair (sp, 127-sp) per block ----
    {
        const int x = blk & 7;
        const int t = blk >> 3;            // 0..127
        const int b = 2 * x + (t >= 64);
        const int sp = (t >= 64) ? t - 64 : t;   // 0..63

        const float* nb = num_t + (size_t)b * (FF + 1) * HH;
        const float* db = den_t + (size_t)b * (FF + 1) * HH;
        float* out_b = out + (size_t)b * (FF * FF * HH);

        comp_slab(nb, db, out_b, sp, tid);
        comp_slab(nb, db, out_b, 127 - sp, tid);
    }
}

extern "C" void kernel_launch(void* const* d_in, const int* in_sizes, int n_in,
                              void* d_out, int out_size, void* d_ws, size_t ws_size,
                              hipStream_t stream) {
    const float* note = (const float*)d_in[0];
    const float* hv   = (const float*)d_in[1];
    const float* W0   = (const float*)d_in[2];
    const float* b0   = (const float*)d_in[3];
    const float* W1   = (const float*)d_in[4];
    const float* b1   = (const float*)d_in[5];
    const float* Wc   = (const float*)d_in[6];
    const float* bc   = (const float*)d_in[7];
    float* out = (float*)d_out;

    float* num_t = (float*)d_ws;
    float* den_t = num_t + TABLE_ELEMS;

    void* args[] = { (void*)&note, (void*)&hv, (void*)&W0, (void*)&b0,
                     (void*)&W1, (void*)&b1, (void*)&Wc, (void*)&bc,
                     (void*)&num_t, (void*)&den_t, (void*)&out };
    hipLaunchCooperativeKernel((const void*)seg_coop, dim3(1024), dim3(256),
                               args, 0, stream);
}

// Round 12
// 128.272 us; speedup vs baseline: 1.4589x; 1.4589x over previous
//
#include <hip/hip_runtime.h>
#include <hip/hip_bf16.h>

#define BB 16
#define FF 128
#define HH 144
#define EE 24
#define C0C 12

typedef float v4f __attribute__((ext_vector_type(4)));

// Workspace (floats): num_t/den_t: [B][F+1][H], then 16 flag ints.
#define TABLE_ELEMS (BB * (FF + 1) * HH)

__device__ __forceinline__ float fastdiv(float n, float d) {
    float r = __builtin_amdgcn_rcpf(d);
    r = fmaf(fmaf(-d, r, 1.0f), r, r);   // one Newton iteration
    return n * r;
}

// Zero the e<s prefix rows of slab sp and slab 127-sp of batch b.
__device__ __forceinline__ void zero_pair_bs(float* __restrict__ out_b, int sp, int tid) {
    v4f* r1 = reinterpret_cast<v4f*>(out_b + (size_t)sp * FF * HH);
    const int n1 = sp * (HH / 4);
    for (int c = tid; c < n1; c += 256) r1[c] = (v4f)(0.f);

    v4f* r2 = reinterpret_cast<v4f*>(out_b + (size_t)(127 - sp) * FF * HH);
    const int n2 = (127 - sp) * (HH / 4);
    for (int c = tid; c < n2; c += 256) r2[c] = (v4f)(0.f);
}

// Full compute triangle of slab s: rows e in [s,128), r = tid/36, step 7.
__device__ __forceinline__ void comp_slab(
    const float* __restrict__ nb, const float* __restrict__ db,
    float* __restrict__ out_b, int s, int tid)
{
    float* ob = out_b + (size_t)s * (FF * HH);
    if (tid < 252) {
        const int r = tid / 36;                   // 0..6
        const int hq = tid - r * 36;              // 0..35
        const int h = hq * 4;

        const v4f n0 = *reinterpret_cast<const v4f*>(nb + (size_t)s * HH + h);
        const v4f d0 = *reinterpret_cast<const v4f*>(db + (size_t)s * HH + h);

        const float* pn = nb + (size_t)(s + r + 1) * HH + h;
        const float* pd_ = db + (size_t)(s + r + 1) * HH + h;
        float* po = ob + (size_t)(s + r) * HH + h;

        #pragma unroll 2
        for (int e = s + r; e < FF; e += 7) {
            const v4f n1 = *reinterpret_cast<const v4f*>(pn);
            const v4f d1 = *reinterpret_cast<const v4f*>(pd_);
            v4f val;
            val.x = fastdiv(n1.x - n0.x, d1.x - d0.x);
            val.y = fastdiv(n1.y - n0.y, d1.y - d0.y);
            val.z = fastdiv(n1.z - n0.z, d1.z - d0.z);
            val.w = fastdiv(n1.w - n0.w, d1.w - d0.w);
            *reinterpret_cast<v4f*>(po) = val;
            pn += 7 * HH;
            pd_ += 7 * HH;
            po += 7 * HH;
        }
    }
}

// Single regular kernel, 1024 blocks x 256 threads. All blocks co-resident
// (4/CU needed; LDS ~20.6KB -> 7/CU cap, VGPR ~52 -> ok), so the flag spin
// cannot deadlock. Blocks 0..143 first build the tables for their
// (b, 16-h tile) and release done[b]; then ALL blocks write their zero
// pair (~11us of stores, hiding table compute), spin (expected ~0) on
// done[b], and write their compute pair.
__global__ __launch_bounds__(256) void seg_one(
    const float* __restrict__ note,   // [B][F][E]
    const float* __restrict__ hv,     // [B][H][E]
    const float* __restrict__ W0,
    const float* __restrict__ b0,
    const float* __restrict__ W1,
    const float* __restrict__ b1,
    const float* __restrict__ Wc,
    const float* __restrict__ bc,
    float* __restrict__ num_t,
    float* __restrict__ den_t,
    int* __restrict__ done,           // [B], zeroed by memsetAsync each call
    float* __restrict__ out)          // [B][F(s)][F(e)][H]
{
    const int blk = blockIdx.x;
    const int tid = threadIdx.x;

    __shared__ float s_hcat[16][EE];   // 1.5 KB
    __shared__ float s_q[16][EE];      // 1.5 KB
    __shared__ float s_p[FF][16];      // 8 KB
    __shared__ float s_pd[FF][16];     // 8 KB
    __shared__ float s_pm[16][16];     // 1 KB
    __shared__ float s_m[16];

    // ---- role 1: table producer (blocks 0..143) ----
    if (blk < 144) {
        const int x = blk & 7;
        const int t = blk >> 3;            // 0..17
        const int b = 2 * x + (t >= 9);
        const int tile = (t >= 9) ? t - 9 : t;   // 0..8
        const int h0 = tile * 16;

        for (int idx = tid; idx < 16 * EE; idx += 256) {
            const int hl = idx / EE, e = idx - hl * EE;
            const float* hvb = hv + ((size_t)b * HH + h0 + hl) * EE;
            float acc;
            if (e < C0C) {
                acc = b0[e];
                #pragma unroll
                for (int j = 0; j < C0C; ++j) acc += W0[e * C0C + j] * hvb[j];
            } else {
                const int e1 = e - C0C;
                acc = b1[e1];
                #pragma unroll
                for (int j = 0; j < C0C; ++j) acc += W1[e1 * C0C + j] * hvb[C0C + j];
            }
            s_hcat[hl][e] = acc;
        }
        __syncthreads();
        for (int idx = tid; idx < 16 * EE; idx += 256) {
            const int hl = idx / EE, e = idx - hl * EE;
            float acc = bc[e];
            #pragma unroll
            for (int j = 0; j < EE; ++j) acc += Wc[e * EE + j] * s_hcat[hl][j];
            s_q[hl][e] = acc;
        }
        __syncthreads();

        const int hl = tid & 15;
        const int f0 = tid >> 4;
        const float scale = 0.20412414523193150818f;  // 1/sqrt(24)
        const float* nb_ = note + (size_t)b * FF * EE;

        float dv[8];
        float pmax = -3.4e38f;
        #pragma unroll
        for (int k = 0; k < 8; ++k) {
            const int f = f0 + (k << 4);
            const float* nr = nb_ + f * EE;
            float acc = 0.f;
            #pragma unroll
            for (int e = 0; e < EE; e += 4) {
                const v4f nv = *reinterpret_cast<const v4f*>(nr + e);
                acc += s_q[hl][e] * nv.x + s_q[hl][e + 1] * nv.y
                     + s_q[hl][e + 2] * nv.z + s_q[hl][e + 3] * nv.w;
            }
            dv[k] = acc;
            pmax = fmaxf(pmax, acc);
        }
        s_pm[f0][hl] = pmax * scale;
        __syncthreads();
        if (tid < 16) {
            float m = s_pm[0][tid];
            #pragma unroll
            for (int r = 1; r < 16; ++r) m = fmaxf(m, s_pm[r][tid]);
            s_m[tid] = m;
        }
        __syncthreads();
        const float m = s_m[hl];

        #pragma unroll
        for (int k = 0; k < 8; ++k) {
            const int f = f0 + (k << 4);
            const float p = __expf(dv[k] * scale - m);
            s_p[f][hl] = p;
            s_pd[f][hl] = p * dv[k];
        }
        __syncthreads();

        for (int off = 1; off < FF; off <<= 1) {
            float tp[8], tpd[8];
            #pragma unroll
            for (int k = 0; k < 8; ++k) {
                const int f = f0 + (k << 4);
                tp[k] = (f >= off) ? s_p[f - off][hl] : 0.f;
                tpd[k] = (f >= off) ? s_pd[f - off][hl] : 0.f;
            }
            __syncthreads();
            #pragma unroll
            for (int k = 0; k < 8; ++k) {
                const int f = f0 + (k << 4);
                if (f >= off) { s_p[f][hl] += tp[k]; s_pd[f][hl] += tpd[k]; }
            }
            __syncthreads();
        }

        const size_t base = (size_t)b * (FF + 1) * HH + h0;
        for (int idx4 = tid; idx4 < 512; idx4 += 256) {
            const int f = idx4 >> 2;           // 0..127
            const int hh = (idx4 & 3) * 4;     // 0,4,8,12
            *reinterpret_cast<v4f*>(num_t + base + (size_t)(f + 1) * HH + hh) =
                *reinterpret_cast<const v4f*>(&s_pd[f][hh]);
            *reinterpret_cast<v4f*>(den_t + base + (size_t)(f + 1) * HH + hh) =
                *reinterpret_cast<const v4f*>(&s_p[f][hh]);
        }
        if (tid < 16) {
            num_t[base + tid] = 0.f;
            den_t[base + tid] = 0.f;
        }

        // release: make table visible device-wide, then bump done[b]
        __threadfence();
        __syncthreads();
        if (tid == 0)
            __hip_atomic_fetch_add(&done[b], 1, __ATOMIC_RELEASE,
                                   __HIP_MEMORY_SCOPE_AGENT);
    }

    // ---- role 2 (all blocks): zero pair, then compute pair ----
    const int x = blk & 7;
    const int t = blk >> 3;            // 0..127
    const int b = 2 * x + (t >= 64);
    const int sp = (t >= 64) ? t - 64 : t;   // 0..63

    float* out_b = out + (size_t)b * (FF * FF * HH);
    zero_pair_bs(out_b, sp, tid);

    // acquire: wait until all 9 table tiles of this b are published
    if (tid == 0) {
        while (__hip_atomic_load(&done[b], __ATOMIC_ACQUIRE,
                                 __HIP_MEMORY_SCOPE_AGENT) < 9) { }
    }
    __syncthreads();

    const float* nb = num_t + (size_t)b * (FF + 1) * HH;
    const float* db = den_t + (size_t)b * (FF + 1) * HH;
    comp_slab(nb, db, out_b, sp, tid);
    comp_slab(nb, db, out_b, 127 - sp, tid);
}

extern "C" void kernel_launch(void* const* d_in, const int* in_sizes, int n_in,
                              void* d_out, int out_size, void* d_ws, size_t ws_size,
                              hipStream_t stream) {
    const float* note = (const float*)d_in[0];
    const float* hv   = (const float*)d_in[1];
    const float* W0   = (const float*)d_in[2];
    const float* b0   = (const float*)d_in[3];
    const float* W1   = (const float*)d_in[4];
    const float* b1   = (const float*)d_in[5];
    const float* Wc   = (const float*)d_in[6];
    const float* bc   = (const float*)d_in[7];
    float* out = (float*)d_out;

    float* num_t = (float*)d_ws;
    float* den_t = num_t + TABLE_ELEMS;
    int* done = (int*)(den_t + TABLE_ELEMS);

    hipMemsetAsync(done, 0, BB * sizeof(int), stream);
    seg_one<<<1024, 256, 0, stream>>>(note, hv, W0, b0, W1, b1, Wc, bc,
                                      num_t, den_t, done, out);
}

// Round 13
// 35.862 us; speedup vs baseline: 5.2183x; 3.5768x over previous
//
#include <hip/hip_runtime.h>
#include <hip/hip_bf16.h>

#define BB 16
#define FF 128
#define HH 144
#define EE 24
#define C0C 12

typedef float v4f __attribute__((ext_vector_type(4)));

// Workspace (floats): num_t/den_t: [B][F+1][H]
#define TABLE_ELEMS (BB * (FF + 1) * HH)

__device__ __forceinline__ float fastdiv(float n, float d) {
    float r = __builtin_amdgcn_rcpf(d);
    r = fmaf(fmaf(-d, r, 1.0f), r, r);   // one Newton iteration
    return n * r;
}

// Kernel A (proven R10): blocks 0..143 compute prefix tables (one per
// (b, 16-h tile)); blocks 144..1167 zero-fill the e<s triangle. Table
// blocks dispatch first; zero stores keep other CUs busy, hiding them.
__global__ __launch_bounds__(256) void seg_pre(
    const float* __restrict__ note,   // [B][F][E]
    const float* __restrict__ hv,     // [B][H][E]
    const float* __restrict__ W0,
    const float* __restrict__ b0,
    const float* __restrict__ W1,
    const float* __restrict__ b1,
    const float* __restrict__ Wc,
    const float* __restrict__ bc,
    float* __restrict__ num_t,
    float* __restrict__ den_t,
    float* __restrict__ out)          // [B][F(s)][F(e)][H]
{
    const int blk = blockIdx.x;
    const int tid = threadIdx.x;

    __shared__ float s_note[FF * EE];  // 12 KB
    __shared__ float s_hcat[16][EE];
    __shared__ float s_q[16][EE];
    __shared__ float s_p[FF][16];      // 8 KB
    __shared__ float s_pd[FF][16];     // 8 KB
    __shared__ float s_pm[16][16];
    __shared__ float s_m[16];

    if (blk >= 144) {
        // ---- zero-fill blocks: pair (sp, 127-sp) of batch b ----
        const int z = blk - 144;       // 0..1023
        const int x = z & 7;
        const int t = z >> 3;          // 0..127
        const int b = 2 * x + (t >= 64);
        const int sp = (t >= 64) ? t - 64 : t;   // 0..63
        float* out_b = out + (size_t)b * (FF * FF * HH);

        v4f* r1 = reinterpret_cast<v4f*>(out_b + (size_t)sp * FF * HH);
        const int n1 = sp * (HH / 4);
        for (int c = tid; c < n1; c += 256) r1[c] = (v4f)(0.f);

        v4f* r2 = reinterpret_cast<v4f*>(out_b + (size_t)(127 - sp) * FF * HH);
        const int n2 = (127 - sp) * (HH / 4);
        for (int c = tid; c < n2; c += 256) r2[c] = (v4f)(0.f);
        return;
    }

    // ---- table blocks: one per (b, 16-h tile) ----
    const int x = blk & 7;
    const int t = blk >> 3;            // 0..17
    const int b = 2 * x + (t >= 9);
    const int tile = (t >= 9) ? t - 9 : t;   // 0..8
    const int h0 = tile * 16;

    const float* nb_ = note + (size_t)b * FF * EE;
    for (int k = tid; k < FF * EE / 4; k += 256)
        reinterpret_cast<v4f*>(s_note)[k] = reinterpret_cast<const v4f*>(nb_)[k];

    for (int idx = tid; idx < 16 * EE; idx += 256) {
        const int hl = idx / EE, e = idx - hl * EE;
        const float* hvb = hv + ((size_t)b * HH + h0 + hl) * EE;
        float acc;
        if (e < C0C) {
            acc = b0[e];
            #pragma unroll
            for (int j = 0; j < C0C; ++j) acc += W0[e * C0C + j] * hvb[j];
        } else {
            const int e1 = e - C0C;
            acc = b1[e1];
            #pragma unroll
            for (int j = 0; j < C0C; ++j) acc += W1[e1 * C0C + j] * hvb[C0C + j];
        }
        s_hcat[hl][e] = acc;
    }
    __syncthreads();
    for (int idx = tid; idx < 16 * EE; idx += 256) {
        const int hl = idx / EE, e = idx - hl * EE;
        float acc = bc[e];
        #pragma unroll
        for (int j = 0; j < EE; ++j) acc += Wc[e * EE + j] * s_hcat[hl][j];
        s_q[hl][e] = acc;
    }
    __syncthreads();

    const int hl = tid & 15;
    const int f0 = tid >> 4;
    const float scale = 0.20412414523193150818f;  // 1/sqrt(24)

    float dv[8];
    float pmax = -3.4e38f;
    #pragma unroll
    for (int k = 0; k < 8; ++k) {
        const int f = f0 + (k << 4);
        float acc = 0.f;
        #pragma unroll
        for (int e = 0; e < EE; ++e) acc += s_q[hl][e] * s_note[f * EE + e];
        dv[k] = acc;
        pmax = fmaxf(pmax, acc);
    }
    s_pm[f0][hl] = pmax * scale;
    __syncthreads();
    if (tid < 16) {
        float m = s_pm[0][tid];
        #pragma unroll
        for (int r = 1; r < 16; ++r) m = fmaxf(m, s_pm[r][tid]);
        s_m[tid] = m;
    }
    __syncthreads();
    const float m = s_m[hl];

    #pragma unroll
    for (int k = 0; k < 8; ++k) {
        const int f = f0 + (k << 4);
        const float p = __expf(dv[k] * scale - m);
        s_p[f][hl] = p;
        s_pd[f][hl] = p * dv[k];
    }
    __syncthreads();

    for (int off = 1; off < FF; off <<= 1) {
        float tp[8], tpd[8];
        #pragma unroll
        for (int k = 0; k < 8; ++k) {
            const int f = f0 + (k << 4);
            tp[k] = (f >= off) ? s_p[f - off][hl] : 0.f;
            tpd[k] = (f >= off) ? s_pd[f - off][hl] : 0.f;
        }
        __syncthreads();
        #pragma unroll
        for (int k = 0; k < 8; ++k) {
            const int f = f0 + (k << 4);
            if (f >= off) { s_p[f][hl] += tp[k]; s_pd[f][hl] += tpd[k]; }
        }
        __syncthreads();
    }

    const size_t base = (size_t)b * (FF + 1) * HH + h0;
    for (int idx4 = tid; idx4 < 512; idx4 += 256) {
        const int f = idx4 >> 2;           // 0..127
        const int hh = (idx4 & 3) * 4;     // 0,4,8,12
        *reinterpret_cast<v4f*>(num_t + base + (size_t)(f + 1) * HH + hh) =
            *reinterpret_cast<const v4f*>(&s_pd[f][hh]);
        *reinterpret_cast<v4f*>(den_t + base + (size_t)(f + 1) * HH + hh) =
            *reinterpret_cast<const v4f*>(&s_p[f][hh]);
    }
    if (tid < 16) {
        num_t[base + tid] = 0.f;
        den_t[base + tid] = 0.f;
    }
}

// Kernel B: block = (b, 16-h slice, group of 4 complementary s-pairs).
// Loads its full table slice (129 rows x 16 h x 2) into LDS ONCE (16.5 KB),
// then writes 8 slabs' compute triangles from LDS. Cuts global table reads
// 4x (152 MB -> 38 MB) vs the per-slab re-read version.
__global__ __launch_bounds__(256) void seg_k2(
    const float* __restrict__ num_t,
    const float* __restrict__ den_t,
    float* __restrict__ out)          // [B][F(s)][F(e)][H]
{
    const int blk = blockIdx.x;        // 2304 = 8 xcd * 288
    const int x = blk & 7;
    const int v = blk >> 3;            // 0..287
    const int b = 2 * x + (v >= 144);
    const int w = (v >= 144) ? v - 144 : v;   // 0..143
    const int hs = w >> 4;             // 0..8
    const int g = w & 15;              // 0..15
    const int h0 = hs * 16;
    const int tid = threadIdx.x;

    __shared__ float s_n[FF + 1][16];  // 8.25 KB
    __shared__ float s_d[FF + 1][16];  // 8.25 KB

    const float* nb = num_t + (size_t)b * (FF + 1) * HH + h0;
    const float* db = den_t + (size_t)b * (FF + 1) * HH + h0;

    // load table slice: (F+1) rows x 16 floats, v4f granularity
    for (int i = tid; i < (FF + 1) * 4; i += 256) {
        const int f = i >> 2;
        const int c = (i & 3) * 4;
        *reinterpret_cast<v4f*>(&s_n[f][c]) =
            *reinterpret_cast<const v4f*>(nb + (size_t)f * HH + c);
        *reinterpret_cast<v4f*>(&s_d[f][c]) =
            *reinterpret_cast<const v4f*>(db + (size_t)f * HH + c);
    }
    __syncthreads();

    // thread -> (c4 = chunk, r = row offset)
    const int c4 = (tid & 3) * 4;
    const int r = tid >> 2;            // 0..63
    float* out_bh = out + (size_t)b * (FF * FF * HH) + h0 + c4;

    #pragma unroll
    for (int pp = 0; pp < 4; ++pp) {
        const int s_lo = g * 4 + pp;   // 0..63
        #pragma unroll
        for (int side = 0; side < 2; ++side) {
            const int s = side ? 127 - s_lo : s_lo;
            const v4f n0 = *reinterpret_cast<const v4f*>(&s_n[s][c4]);
            const v4f d0 = *reinterpret_cast<const v4f*>(&s_d[s][c4]);
            float* os = out_bh + (size_t)s * (FF * HH);

            int e = s + r;
            #pragma unroll
            for (int k = 0; k < 2; ++k, e += 64) {
                if (e < FF) {
                    const v4f n1 = *reinterpret_cast<const v4f*>(&s_n[e + 1][c4]);
                    const v4f d1 = *reinterpret_cast<const v4f*>(&s_d[e + 1][c4]);
                    v4f val;
                    val.x = fastdiv(n1.x - n0.x, d1.x - d0.x);
                    val.y = fastdiv(n1.y - n0.y, d1.y - d0.y);
                    val.z = fastdiv(n1.z - n0.z, d1.z - d0.z);
                    val.w = fastdiv(n1.w - n0.w, d1.w - d0.w);
                    *reinterpret_cast<v4f*>(os + (size_t)e * HH) = val;
                }
            }
        }
    }
}

extern "C" void kernel_launch(void* const* d_in, const int* in_sizes, int n_in,
                              void* d_out, int out_size, void* d_ws, size_t ws_size,
                              hipStream_t stream) {
    const float* note = (const float*)d_in[0];
    const float* hv   = (const float*)d_in[1];
    const float* W0   = (const float*)d_in[2];
    const float* b0   = (const float*)d_in[3];
    const float* W1   = (const float*)d_in[4];
    const float* b1   = (const float*)d_in[5];
    const float* Wc   = (const float*)d_in[6];
    const float* bc   = (const float*)d_in[7];
    float* out = (float*)d_out;

    float* num_t = (float*)d_ws;
    float* den_t = num_t + TABLE_ELEMS;

    seg_pre<<<144 + 1024, 256, 0, stream>>>(note, hv, W0, b0, W1, b1, Wc, bc,
                                            num_t, den_t, out);
    seg_k2<<<2304, 256, 0, stream>>>(num_t, den_t, out);
}

// Round 14
// 34.192 us; speedup vs baseline: 5.4731x; 1.0488x over previous
//
#include <hip/hip_runtime.h>
#include <hip/hip_bf16.h>

#define BB 16
#define FF 128
#define HH 144
#define EE 24
#define C0C 12

typedef float v4f __attribute__((ext_vector_type(4)));

// Workspace (floats): num_t/den_t: [B][F+1][H]
#define TABLE_ELEMS (BB * (FF + 1) * HH)

__device__ __forceinline__ float fastdiv(float n, float d) {
    float r = __builtin_amdgcn_rcpf(d);
    r = fmaf(fmaf(-d, r, 1.0f), r, r);   // one Newton iteration
    return n * r;
}

// Kernel A (proven R10): blocks 0..143 compute prefix tables (one per
// (b, 16-h tile)); blocks 144..1167 zero-fill the e<s triangle. Table
// blocks dispatch first; zero stores keep other CUs busy, hiding them.
__global__ __launch_bounds__(256) void seg_pre(
    const float* __restrict__ note,   // [B][F][E]
    const float* __restrict__ hv,     // [B][H][E]
    const float* __restrict__ W0,
    const float* __restrict__ b0,
    const float* __restrict__ W1,
    const float* __restrict__ b1,
    const float* __restrict__ Wc,
    const float* __restrict__ bc,
    float* __restrict__ num_t,
    float* __restrict__ den_t,
    float* __restrict__ out)          // [B][F(s)][F(e)][H]
{
    const int blk = blockIdx.x;
    const int tid = threadIdx.x;

    __shared__ float s_note[FF * EE];  // 12 KB
    __shared__ float s_hcat[16][EE];
    __shared__ float s_q[16][EE];
    __shared__ float s_p[FF][16];      // 8 KB
    __shared__ float s_pd[FF][16];     // 8 KB
    __shared__ float s_pm[16][16];
    __shared__ float s_m[16];

    if (blk >= 144) {
        // ---- zero-fill blocks: pair (sp, 127-sp) of batch b ----
        const int z = blk - 144;       // 0..1023
        const int x = z & 7;
        const int t = z >> 3;          // 0..127
        const int b = 2 * x + (t >= 64);
        const int sp = (t >= 64) ? t - 64 : t;   // 0..63
        float* out_b = out + (size_t)b * (FF * FF * HH);

        v4f* r1 = reinterpret_cast<v4f*>(out_b + (size_t)sp * FF * HH);
        const int n1 = sp * (HH / 4);
        for (int c = tid; c < n1; c += 256) r1[c] = (v4f)(0.f);

        v4f* r2 = reinterpret_cast<v4f*>(out_b + (size_t)(127 - sp) * FF * HH);
        const int n2 = (127 - sp) * (HH / 4);
        for (int c = tid; c < n2; c += 256) r2[c] = (v4f)(0.f);
        return;
    }

    // ---- table blocks: one per (b, 16-h tile) ----
    const int x = blk & 7;
    const int t = blk >> 3;            // 0..17
    const int b = 2 * x + (t >= 9);
    const int tile = (t >= 9) ? t - 9 : t;   // 0..8
    const int h0 = tile * 16;

    const float* nb_ = note + (size_t)b * FF * EE;
    for (int k = tid; k < FF * EE / 4; k += 256)
        reinterpret_cast<v4f*>(s_note)[k] = reinterpret_cast<const v4f*>(nb_)[k];

    for (int idx = tid; idx < 16 * EE; idx += 256) {
        const int hl = idx / EE, e = idx - hl * EE;
        const float* hvb = hv + ((size_t)b * HH + h0 + hl) * EE;
        float acc;
        if (e < C0C) {
            acc = b0[e];
            #pragma unroll
            for (int j = 0; j < C0C; ++j) acc += W0[e * C0C + j] * hvb[j];
        } else {
            const int e1 = e - C0C;
            acc = b1[e1];
            #pragma unroll
            for (int j = 0; j < C0C; ++j) acc += W1[e1 * C0C + j] * hvb[C0C + j];
        }
        s_hcat[hl][e] = acc;
    }
    __syncthreads();
    for (int idx = tid; idx < 16 * EE; idx += 256) {
        const int hl = idx / EE, e = idx - hl * EE;
        float acc = bc[e];
        #pragma unroll
        for (int j = 0; j < EE; ++j) acc += Wc[e * EE + j] * s_hcat[hl][j];
        s_q[hl][e] = acc;
    }
    __syncthreads();

    const int hl = tid & 15;
    const int f0 = tid >> 4;
    const float scale = 0.20412414523193150818f;  // 1/sqrt(24)

    float dv[8];
    float pmax = -3.4e38f;
    #pragma unroll
    for (int k = 0; k < 8; ++k) {
        const int f = f0 + (k << 4);
        float acc = 0.f;
        #pragma unroll
        for (int e = 0; e < EE; ++e) acc += s_q[hl][e] * s_note[f * EE + e];
        dv[k] = acc;
        pmax = fmaxf(pmax, acc);
    }
    s_pm[f0][hl] = pmax * scale;
    __syncthreads();
    if (tid < 16) {
        float m = s_pm[0][tid];
        #pragma unroll
        for (int r = 1; r < 16; ++r) m = fmaxf(m, s_pm[r][tid]);
        s_m[tid] = m;
    }
    __syncthreads();
    const float m = s_m[hl];

    #pragma unroll
    for (int k = 0; k < 8; ++k) {
        const int f = f0 + (k << 4);
        const float p = __expf(dv[k] * scale - m);
        s_p[f][hl] = p;
        s_pd[f][hl] = p * dv[k];
    }
    __syncthreads();

    for (int off = 1; off < FF; off <<= 1) {
        float tp[8], tpd[8];
        #pragma unroll
        for (int k = 0; k < 8; ++k) {
            const int f = f0 + (k << 4);
            tp[k] = (f >= off) ? s_p[f - off][hl] : 0.f;
            tpd[k] = (f >= off) ? s_pd[f - off][hl] : 0.f;
        }
        __syncthreads();
        #pragma unroll
        for (int k = 0; k < 8; ++k) {
            const int f = f0 + (k << 4);
            if (f >= off) { s_p[f][hl] += tp[k]; s_pd[f][hl] += tpd[k]; }
        }
        __syncthreads();
    }

    const size_t base = (size_t)b * (FF + 1) * HH + h0;
    for (int idx4 = tid; idx4 < 512; idx4 += 256) {
        const int f = idx4 >> 2;           // 0..127
        const int hh = (idx4 & 3) * 4;     // 0,4,8,12
        *reinterpret_cast<v4f*>(num_t + base + (size_t)(f + 1) * HH + hh) =
            *reinterpret_cast<const v4f*>(&s_pd[f][hh]);
        *reinterpret_cast<v4f*>(den_t + base + (size_t)(f + 1) * HH + hh) =
            *reinterpret_cast<const v4f*>(&s_p[f][hh]);
    }
    if (tid < 16) {
        num_t[base + tid] = 0.f;
        den_t[base + tid] = 0.f;
    }
}

// Kernel B: compute triangle rows of parity `half` in slab s; full-row
// wave stores (1 KB contiguous per wave). 1-deep software prefetch keeps
// next iteration's L2 table loads in flight during current compute.
__device__ __forceinline__ void k2_row_half(
    const float* __restrict__ nb, const float* __restrict__ db,
    float* __restrict__ out_b, int s, int tid, int half)
{
    float* ob = out_b + (size_t)s * (FF * HH);

    if (tid < 252) {
        const int r = tid / 36;                   // 0..6
        const int hq = tid - r * 36;              // 0..35
        const int h = hq * 4;

        const v4f n0 = *reinterpret_cast<const v4f*>(nb + (size_t)s * HH + h);
        const v4f d0 = *reinterpret_cast<const v4f*>(db + (size_t)s * HH + h);

        const int e0 = s + r + 7 * half;
        const int cnt = (e0 < FF) ? ((FF - e0 + 13) / 14) : 0;

        const float* pn = nb + (size_t)(e0 + 1) * HH + h;
        const float* pd_ = db + (size_t)(e0 + 1) * HH + h;
        float* po = ob + (size_t)e0 * HH + h;

        if (cnt > 0) {
            v4f n1 = *reinterpret_cast<const v4f*>(pn);
            v4f d1 = *reinterpret_cast<const v4f*>(pd_);
            #pragma unroll 2
            for (int i = 1; i < cnt; ++i) {
                pn += 14 * HH;
                pd_ += 14 * HH;
                const v4f n2 = *reinterpret_cast<const v4f*>(pn);
                const v4f d2 = *reinterpret_cast<const v4f*>(pd_);
                v4f val;
                val.x = fastdiv(n1.x - n0.x, d1.x - d0.x);
                val.y = fastdiv(n1.y - n0.y, d1.y - d0.y);
                val.z = fastdiv(n1.z - n0.z, d1.z - d0.z);
                val.w = fastdiv(n1.w - n0.w, d1.w - d0.w);
                *reinterpret_cast<v4f*>(po) = val;
                po += 14 * HH;
                n1 = n2;
                d1 = d2;
            }
            v4f val;
            val.x = fastdiv(n1.x - n0.x, d1.x - d0.x);
            val.y = fastdiv(n1.y - n0.y, d1.y - d0.y);
            val.z = fastdiv(n1.z - n0.z, d1.z - d0.z);
            val.w = fastdiv(n1.w - n0.w, d1.w - d0.w);
            *reinterpret_cast<v4f*>(po) = val;
        }
    }
}

__global__ __launch_bounds__(256) void seg_k2(
    const float* __restrict__ num_t,
    const float* __restrict__ den_t,
    float* __restrict__ out)          // [B][F(s)][F(e)][H]
{
    // XCD swizzle: xcd = blk&7 owns b in {2*xcd, 2*xcd+1} -> table slice
    // (0.74 MB) stays resident in that XCD's 4 MB L2.
    const int blk = blockIdx.x;        // 2048
    const int x = blk & 7;
    const int t = blk >> 3;            // 0..255
    const int b = 2 * x + (t >= 128);
    const int j = t & 127;
    const int sp = j >> 1;             // 0..63
    const int half = j & 1;
    const int tid = threadIdx.x;

    const float* nb = num_t + (size_t)b * (FF + 1) * HH;
    const float* db = den_t + (size_t)b * (FF + 1) * HH;
    float* out_b = out + (size_t)b * (FF * FF * HH);

    // paired s values: constant compute-row count per block
    k2_row_half(nb, db, out_b, sp, tid, half);
    k2_row_half(nb, db, out_b, 127 - sp, tid, half);
}

extern "C" void kernel_launch(void* const* d_in, const int* in_sizes, int n_in,
                              void* d_out, int out_size, void* d_ws, size_t ws_size,
                              hipStream_t stream) {
    const float* note = (const float*)d_in[0];
    const float* hv   = (const float*)d_in[1];
    const float* W0   = (const float*)d_in[2];
    const float* b0   = (const float*)d_in[3];
    const float* W1   = (const float*)d_in[4];
    const float* b1   = (const float*)d_in[5];
    const float* Wc   = (const float*)d_in[6];
    const float* bc   = (const float*)d_in[7];
    float* out = (float*)d_out;

    float* num_t = (float*)d_ws;
    float* den_t = num_t + TABLE_ELEMS;

    seg_pre<<<144 + 1024, 256, 0, stream>>>(note, hv, W0, b0, W1, b1, Wc, bc,
                                            num_t, den_t, out);
    seg_k2<<<BB * FF, 256, 0, stream>>>(num_t, den_t, out);
}

// Round 15
// 33.990 us; speedup vs baseline: 5.5057x; 1.0060x over previous
//
#include <hip/hip_runtime.h>
#include <hip/hip_bf16.h>

#define BB 16
#define FF 128
#define HH 144
#define EE 24
#define C0C 12

typedef float v4f __attribute__((ext_vector_type(4)));

// Workspace (floats): packed table pk: [B][F+1][H][2] = {num, den}
// element offset: ((b*(F+1) + f)*H + h)*2
#define PK_ELEMS (BB * (FF + 1) * HH * 2)

__device__ __forceinline__ float fastdiv(float n, float d) {
    float r = __builtin_amdgcn_rcpf(d);
    r = fmaf(fmaf(-d, r, 1.0f), r, r);   // one Newton iteration
    return n * r;
}

// Kernel A: blocks 0..143 compute prefix tables (one per (b, 16-h tile));
// blocks 144..1167 zero-fill the e<s triangle. Table blocks dispatch first;
// zero stores keep the other CUs saturated, hiding table compute.
__global__ __launch_bounds__(256) void seg_pre(
    const float* __restrict__ note,   // [B][F][E]
    const float* __restrict__ hv,     // [B][H][E]
    const float* __restrict__ W0,
    const float* __restrict__ b0,
    const float* __restrict__ W1,
    const float* __restrict__ b1,
    const float* __restrict__ Wc,
    const float* __restrict__ bc,
    float* __restrict__ pk,
    float* __restrict__ out)          // [B][F(s)][F(e)][H]
{
    const int blk = blockIdx.x;
    const int tid = threadIdx.x;

    __shared__ float s_note[FF * EE];  // 12 KB
    __shared__ float s_hcat[16][EE];
    __shared__ float s_q[16][EE];
    __shared__ float s_p[FF][16];      // 8 KB
    __shared__ float s_pd[FF][16];     // 8 KB
    __shared__ float s_pm[16][16];
    __shared__ float s_m[16];

    if (blk >= 144) {
        // ---- zero-fill blocks: pair (sp, 127-sp) of batch b ----
        const int z = blk - 144;       // 0..1023
        const int x = z & 7;
        const int t = z >> 3;          // 0..127
        const int b = 2 * x + (t >= 64);
        const int sp = (t >= 64) ? t - 64 : t;   // 0..63
        float* out_b = out + (size_t)b * (FF * FF * HH);

        v4f* r1 = reinterpret_cast<v4f*>(out_b + (size_t)sp * FF * HH);
        const int n1 = sp * (HH / 4);
        for (int c = tid; c < n1; c += 256) r1[c] = (v4f)(0.f);

        v4f* r2 = reinterpret_cast<v4f*>(out_b + (size_t)(127 - sp) * FF * HH);
        const int n2 = (127 - sp) * (HH / 4);
        for (int c = tid; c < n2; c += 256) r2[c] = (v4f)(0.f);
        return;
    }

    // ---- table blocks: one per (b, 16-h tile) ----
    const int x = blk & 7;
    const int t = blk >> 3;            // 0..17
    const int b = 2 * x + (t >= 9);
    const int tile = (t >= 9) ? t - 9 : t;   // 0..8
    const int h0 = tile * 16;

    const float* nb_ = note + (size_t)b * FF * EE;
    for (int k = tid; k < FF * EE / 4; k += 256)
        reinterpret_cast<v4f*>(s_note)[k] = reinterpret_cast<const v4f*>(nb_)[k];

    for (int idx = tid; idx < 16 * EE; idx += 256) {
        const int hl = idx / EE, e = idx - hl * EE;
        const float* hvb = hv + ((size_t)b * HH + h0 + hl) * EE;
        float acc;
        if (e < C0C) {
            acc = b0[e];
            #pragma unroll
            for (int j = 0; j < C0C; ++j) acc += W0[e * C0C + j] * hvb[j];
        } else {
            const int e1 = e - C0C;
            acc = b1[e1];
            #pragma unroll
            for (int j = 0; j < C0C; ++j) acc += W1[e1 * C0C + j] * hvb[C0C + j];
        }
        s_hcat[hl][e] = acc;
    }
    __syncthreads();
    for (int idx = tid; idx < 16 * EE; idx += 256) {
        const int hl = idx / EE, e = idx - hl * EE;
        float acc = bc[e];
        #pragma unroll
        for (int j = 0; j < EE; ++j) acc += Wc[e * EE + j] * s_hcat[hl][j];
        s_q[hl][e] = acc;
    }
    __syncthreads();

    const int hl = tid & 15;
    const int f0 = tid >> 4;
    const float scale = 0.20412414523193150818f;  // 1/sqrt(24)

    float dv[8];
    float pmax = -3.4e38f;
    #pragma unroll
    for (int k = 0; k < 8; ++k) {
        const int f = f0 + (k << 4);
        float acc = 0.f;
        #pragma unroll
        for (int e = 0; e < EE; ++e) acc += s_q[hl][e] * s_note[f * EE + e];
        dv[k] = acc;
        pmax = fmaxf(pmax, acc);
    }
    s_pm[f0][hl] = pmax * scale;
    __syncthreads();
    if (tid < 16) {
        float m = s_pm[0][tid];
        #pragma unroll
        for (int r = 1; r < 16; ++r) m = fmaxf(m, s_pm[r][tid]);
        s_m[tid] = m;
    }
    __syncthreads();
    const float m = s_m[hl];

    #pragma unroll
    for (int k = 0; k < 8; ++k) {
        const int f = f0 + (k << 4);
        const float p = __expf(dv[k] * scale - m);
        s_p[f][hl] = p;
        s_pd[f][hl] = p * dv[k];
    }
    __syncthreads();

    for (int off = 1; off < FF; off <<= 1) {
        float tp[8], tpd[8];
        #pragma unroll
        for (int k = 0; k < 8; ++k) {
            const int f = f0 + (k << 4);
            tp[k] = (f >= off) ? s_p[f - off][hl] : 0.f;
            tpd[k] = (f >= off) ? s_pd[f - off][hl] : 0.f;
        }
        __syncthreads();
        #pragma unroll
        for (int k = 0; k < 8; ++k) {
            const int f = f0 + (k << 4);
            if (f >= off) { s_p[f][hl] += tp[k]; s_pd[f][hl] += tpd[k]; }
        }
        __syncthreads();
    }

    // write packed table: {num,den} interleaved; v4f covers 2 h values
    // element offset ((b*(F+1)+f)*H + h)*2
    float* pkb = pk + ((size_t)b * (FF + 1) * HH + h0) * 2;
    for (int idx4 = tid; idx4 < 1024; idx4 += 256) {
        const int f = idx4 >> 3;           // 0..127
        const int hh = (idx4 & 7) * 2;     // 0,2,..,14
        v4f val;
        val.x = s_pd[f][hh];               // num
        val.y = s_p[f][hh];                // den
        val.z = s_pd[f][hh + 1];
        val.w = s_p[f][hh + 1];
        *reinterpret_cast<v4f*>(pkb + ((size_t)(f + 1) * HH + hh) * 2) = val;
    }
    if (tid < 8) {
        *reinterpret_cast<v4f*>(pkb + tid * 4) = (v4f)(0.f);   // row 0 zeros
    }
}

// Kernel B: block = (b, pair of consecutive s {a,a+1} + complements, quarter).
// One packed-row read (32 B/thread) serves TWO slab stores -> table reads
// halved (151 -> 76 MB) at identical full-row store pattern.
__global__ __launch_bounds__(256) void seg_k2(
    const float* __restrict__ pk,
    float* __restrict__ out)          // [B][F(s)][F(e)][H]
{
    const int blk = blockIdx.x;        // 2048 = 8 xcd * 2 b * 32 g * 4 q
    const int x = blk & 7;
    const int rest = blk >> 3;         // 0..255
    const int bsel = rest >> 7;        // 0/1
    const int r2 = rest & 127;
    const int g = r2 >> 2;             // 0..31
    const int q = r2 & 3;              // 0..3
    const int b = 2 * x + bsel;
    const int tid = threadIdx.x;
    if (tid >= 252) return;

    const int r = tid / 36;            // 0..6
    const int hq = tid - r * 36;       // 0..35
    const int h = hq * 4;

    const float* tb = pk + (size_t)b * (FF + 1) * (HH * 2);
    float* out_b = out + (size_t)b * (FF * FF * HH);

    #pragma unroll
    for (int side = 0; side < 2; ++side) {
        const int a = side ? 126 - 2 * g : 2 * g;   // {a, a+1} slabs

        // n0/d0 packed rows for s=a and s=a+1, this thread's 4 h
        const v4f za_lo = *reinterpret_cast<const v4f*>(tb + ((size_t)a * HH + h) * 2);
        const v4f za_hi = *reinterpret_cast<const v4f*>(tb + ((size_t)a * HH + h) * 2 + 4);
        const v4f zb_lo = *reinterpret_cast<const v4f*>(tb + ((size_t)(a + 1) * HH + h) * 2);
        const v4f zb_hi = *reinterpret_cast<const v4f*>(tb + ((size_t)(a + 1) * HH + h) * 2 + 4);

        float* ob0 = out_b + (size_t)a * (FF * HH) + h;
        float* ob1 = out_b + (size_t)(a + 1) * (FF * HH) + h;

        for (int e = a + r + 7 * q; e < FF; e += 28) {
            const v4f t_lo = *reinterpret_cast<const v4f*>(tb + ((size_t)(e + 1) * HH + h) * 2);
            const v4f t_hi = *reinterpret_cast<const v4f*>(tb + ((size_t)(e + 1) * HH + h) * 2 + 4);

            v4f v0;
            v0.x = fastdiv(t_lo.x - za_lo.x, t_lo.y - za_lo.y);
            v0.y = fastdiv(t_lo.z - za_lo.z, t_lo.w - za_lo.w);
            v0.z = fastdiv(t_hi.x - za_hi.x, t_hi.y - za_hi.y);
            v0.w = fastdiv(t_hi.z - za_hi.z, t_hi.w - za_hi.w);
            *reinterpret_cast<v4f*>(ob0 + (size_t)e * HH) = v0;

            if (e > a) {               // slab a+1 needs e >= a+1
                v4f v1;
                v1.x = fastdiv(t_lo.x - zb_lo.x, t_lo.y - zb_lo.y);
                v1.y = fastdiv(t_lo.z - zb_lo.z, t_lo.w - zb_lo.w);
                v1.z = fastdiv(t_hi.x - zb_hi.x, t_hi.y - zb_hi.y);
                v1.w = fastdiv(t_hi.z - zb_hi.z, t_hi.w - zb_hi.w);
                *reinterpret_cast<v4f*>(ob1 + (size_t)e * HH) = v1;
            }
        }
    }
}

extern "C" void kernel_launch(void* const* d_in, const int* in_sizes, int n_in,
                              void* d_out, int out_size, void* d_ws, size_t ws_size,
                              hipStream_t stream) {
    const float* note = (const float*)d_in[0];
    const float* hv   = (const float*)d_in[1];
    const float* W0   = (const float*)d_in[2];
    const float* b0   = (const float*)d_in[3];
    const float* W1   = (const float*)d_in[4];
    const float* b1   = (const float*)d_in[5];
    const float* Wc   = (const float*)d_in[6];
    const float* bc   = (const float*)d_in[7];
    float* out = (float*)d_out;

    float* pk = (float*)d_ws;

    seg_pre<<<144 + 1024, 256, 0, stream>>>(note, hv, W0, b0, W1, b1, Wc, bc,
                                            pk, out);
    seg_k2<<<2048, 256, 0, stream>>>(pk, out);
}